// Round 8
// baseline (360.984 us; speedup 1.0000x reference)
//
#include <hip/hip_runtime.h>
#include <hip/hip_bf16.h>
#include <math.h>

#define N_NODES   50000
#define N_EDGES   800000
#define N_GRAPHS  64
#define IN_CH     128
#define GLOBAL_DIM 256
#define HIDDEN    64
#define HEADS     4
#define N_CLASSES 10
#define QKV_COLS  832   // 256 q | 256 k | 256 v | 64 skip
#define MAXDEG    64

// bucket scatter (atomic-free CSR build)
#define P1B    256      // pass-1 blocks
#define EPB    3125     // edges per pass-1 block (256*3125 = 800000 exact)
#define NBUCK  196      // ceil(50000/256) buckets of 256 nodes
#define SLABP  48       // slots per (bucket,block): mean 15.9, sd 4.0 -> 8sigma

// x -> bf16 conversion blocks in prep
#define XCB    3125     // 3125 * 256 * 8 = 6.4M elements exact

typedef unsigned short ushort_t;
typedef unsigned int uint_t;
typedef unsigned char uchar_t;
typedef __attribute__((ext_vector_type(8))) short short8;
typedef __attribute__((ext_vector_type(4))) float floatx4;
typedef __attribute__((ext_vector_type(2))) float floatx2;

// ---------------------------------------------------------------------------
// helpers
// ---------------------------------------------------------------------------
__device__ __forceinline__ ushort_t bf16rne(float f) {
    uint_t b = __float_as_uint(f);
    b += 0x7fffu + ((b >> 16) & 1u);
    return (ushort_t)(b >> 16);
}
__device__ __forceinline__ float4 bf4_unpack(uint_t lo, uint_t hi) {
    float4 f;
    f.x = __uint_as_float(lo << 16);
    f.y = __uint_as_float(lo & 0xffff0000u);
    f.z = __uint_as_float(hi << 16);
    f.w = __uint_as_float(hi & 0xffff0000u);
    return f;
}
__device__ __forceinline__ uchar_t fp8e4m3(float f) {
    int v = __builtin_amdgcn_cvt_pk_fp8_f32(f, 0.f, 0, false);
    return (uchar_t)(v & 0xff);
}
__device__ __forceinline__ short8 pack_bf8(float4 a, float4 b) {
    union { short8 s; ushort_t u[8]; } r;
    r.u[0] = bf16rne(a.x); r.u[1] = bf16rne(a.y);
    r.u[2] = bf16rne(a.z); r.u[3] = bf16rne(a.w);
    r.u[4] = bf16rne(b.x); r.u[5] = bf16rne(b.y);
    r.u[6] = bf16rne(b.z); r.u[7] = bf16rne(b.w);
    return r.s;
}
__device__ __forceinline__ void graph_range(const int* __restrict__ batch, int g,
                                            int& start, int& end) {
    int lo = 0, hi = N_NODES;
    while (lo < hi) { int mid = (lo + hi) >> 1; if (batch[mid] < g) lo = mid + 1; else hi = mid; }
    start = lo;
    hi = N_NODES;
    while (lo < hi) { int mid = (lo + hi) >> 1; if (batch[mid] < g + 1) lo = mid + 1; else hi = mid; }
    end = lo;
}

// ---------------------------------------------------------------------------
// PREP: weight concat [0,624) || pass-1 bucket scatter [624,880) ||
//       x fp32->bf16 conversion [880, 880+3125)
// ---------------------------------------------------------------------------
#define PREP_CONC_B  624

__global__ __launch_bounds__(256) void prep_p1(
        const float* __restrict__ W1q, const float* __restrict__ W1k,
        const float* __restrict__ W1v, const float* __restrict__ W1s,
        const float* __restrict__ b1q, const float* __restrict__ b1k,
        const float* __restrict__ b1v, const float* __restrict__ b1s,
        const float* __restrict__ W2q, const float* __restrict__ W2k,
        const float* __restrict__ W2v, const float* __restrict__ W2s,
        const float* __restrict__ b2q, const float* __restrict__ b2k,
        const float* __restrict__ b2v, const float* __restrict__ b2s,
        ushort_t* __restrict__ Wt1, ushort_t* __restrict__ Wt2,
        float* __restrict__ bcat1, float* __restrict__ bcat2,
        const int* __restrict__ src, const int* __restrict__ dst,
        uint_t* __restrict__ slab, int* __restrict__ cntm,
        const float* __restrict__ x, ushort_t* __restrict__ xb) {
    int b = blockIdx.x, t = threadIdx.x;
    if (b >= PREP_CONC_B + P1B) {
        // ---- x conversion: 8 floats per thread ----
        int base = (b - (PREP_CONC_B + P1B)) * 2048 + t * 8;
        float4 f0 = *(const float4*)(x + base);
        float4 f1 = *(const float4*)(x + base + 4);
        *(short8*)(xb + base) = pack_bf8(f0, f1);
        return;
    }
    if (b >= PREP_CONC_B) {
        int blk = b - PREP_CONC_B;
        __shared__ int hist[NBUCK];
        for (int i = t; i < NBUCK; i += 256) hist[i] = 0;
        __syncthreads();
        int e0 = blk * EPB;
        int e1 = e0 + EPB;
        for (int e = e0 + t; e < e1; e += 256) {
            int s = src[e], d = dst[e];
            int bu = d >> 8;
            int off = atomicAdd(&hist[bu], 1);
            if (off < SLABP)
                slab[((size_t)bu * P1B + blk) * SLABP + off] =
                    ((uint_t)d << 16) | (uint_t)s;
        }
        __syncthreads();
        for (int i = t; i < NBUCK; i += 256)
            cntm[i * P1B + blk] = hist[i] < SLABP ? hist[i] : SLABP;
        return;
    }
    int idx = b * 256 + t;
    const int T1 = IN_CH * QKV_COLS;
    const int T2 = HIDDEN * QKV_COLS;
    if (idx < T1) {
        int c = idx / IN_CH, k = idx % IN_CH;
        float v;
        if (c < 256)      v = W1q[k * 256 + c];
        else if (c < 512) v = W1k[k * 256 + (c - 256)];
        else if (c < 768) v = W1v[k * 256 + (c - 512)];
        else              v = W1s[k * 64  + (c - 768)];
        Wt1[idx] = bf16rne(v);
    } else if (idx < T1 + T2) {
        int i2 = idx - T1;
        int c = i2 / HIDDEN, k = i2 % HIDDEN;
        float v;
        if (c < 256)      v = W2q[k * 256 + c];
        else if (c < 512) v = W2k[k * 256 + (c - 256)];
        else if (c < 768) v = W2v[k * 256 + (c - 512)];
        else              v = W2s[k * 64  + (c - 768)];
        Wt2[i2] = bf16rne(v);
    }
    if (idx < QKV_COLS) {
        float bb, b2;
        if (idx < 256)      { bb = b1q[idx];       b2 = b2q[idx]; }
        else if (idx < 512) { bb = b1k[idx - 256]; b2 = b2k[idx - 256]; }
        else if (idx < 768) { bb = b1v[idx - 512]; b2 = b2v[idx - 512]; }
        else                { bb = b1s[idx - 768]; b2 = b2s[idx - 768]; }
        bcat1[idx] = bb;
        bcat2[idx] = b2;
    }
}

// ---------------------------------------------------------------------------
// GEMM v12 body: 64-row strips, 1 row-tile per wave (acc 32 VGPR), A always
// bf16 (xb for conv1). 7 groups: g 0-5 = 128-col qkv tiles, g6 = 64-col skip.
// K=128: two-stage B (64 cols each, LDS 17.4KB). K=64: single-stage (18.4KB).
// kv interleave: chunk i (16B) = k[8i..8i+7] || v[8i..8i+7].
// ---------------------------------------------------------------------------
template <int K>
__device__ __forceinline__ void gemm_body12(int idx0, int t,
                                            const ushort_t* __restrict__ A,
                                            const ushort_t* __restrict__ Wt,
                                            const float* __restrict__ bias,
                                            uchar_t* __restrict__ qb8,
                                            uchar_t* __restrict__ kvb,
                                            ushort_t* __restrict__ skipb,
                                            int N, int RB, uchar_t* smem) {
    constexpr int KP = K + 8;
    constexpr int C8 = K / 8;
    ushort_t* Bs = (ushort_t*)smem;

    const int xcd = idx0 & 7;
    const int j = idx0 >> 3;
    const int g = j % 7;
    const int strip = (j / 7) * 8 + xcd;
    if (strip >= RB) return;
    const int base_r = strip * 64;

    const int wave = t >> 6, lane = t & 63;
    const int quad = lane >> 4, m16 = lane & 15;

    // A fragments: wave handles rows base_r + wave*16 .. +15; once per block.
    int arow = base_r + wave * 16 + m16;
    int cr = arow < N ? arow : N - 1;
    const ushort_t* Ar = A + (size_t)cr * K + quad * 8;
    short8 a[K / 32];
#pragma unroll
    for (int kc = 0; kc < K / 32; ++kc) a[kc] = *(const short8*)(Ar + kc * 32);

    if (g < 6) {
        const int base_c = g * 128;
        floatx4 acc[8];
#pragma unroll
        for (int c2 = 0; c2 < 8; ++c2) acc[c2] = (floatx4){0.f, 0.f, 0.f, 0.f};

        if (K == 128) {
            // two-stage: 64 cols per stage, Bs reused
#pragma unroll
            for (int hc = 0; hc < 2; ++hc) {
                if (hc) __syncthreads();   // all waves done with half 0
#pragma unroll
                for (int i = 0; i < 4; ++i) {
                    int ii = t + i * 256;
                    int n = ii / C8, c = ii % C8;
                    *(uint4*)(Bs + n * KP + c * 8) =
                        *(const uint4*)(Wt + (size_t)(base_c + hc * 64 + n) * K + c * 8);
                }
                __syncthreads();
#pragma unroll
                for (int kc = 0; kc < K / 32; ++kc) {
                    int ko = kc * 32 + quad * 8;
#pragma unroll
                    for (int c2 = 0; c2 < 4; ++c2) {
                        short8 b = *(const short8*)(Bs + (c2 * 16 + m16) * KP + ko);
                        acc[hc * 4 + c2] =
                            __builtin_amdgcn_mfma_f32_16x16x32_bf16(a[kc], b, acc[hc * 4 + c2], 0, 0, 0);
                    }
                }
            }
        } else {
            // single-stage: all 128 cols
#pragma unroll
            for (int i = 0; i < 4; ++i) {
                int ii = t + i * 256;
                int n = ii / C8, c = ii % C8;
                *(uint4*)(Bs + n * KP + c * 8) =
                    *(const uint4*)(Wt + (size_t)(base_c + n) * K + c * 8);
            }
            __syncthreads();
#pragma unroll
            for (int kc = 0; kc < K / 32; ++kc) {
                int ko = kc * 32 + quad * 8;
#pragma unroll
                for (int c2 = 0; c2 < 8; ++c2) {
                    short8 b = *(const short8*)(Bs + (c2 * 16 + m16) * KP + ko);
                    acc[c2] = __builtin_amdgcn_mfma_f32_16x16x32_bf16(a[kc], b, acc[c2], 0, 0, 0);
                }
            }
        }

#pragma unroll
        for (int c2 = 0; c2 < 8; ++c2) {
            float bb = bias[base_c + c2 * 16 + m16];
#pragma unroll
            for (int r = 0; r < 4; ++r) acc[c2][r] += bb;
        }

        __syncthreads();   // Bs free -> epilogue tile
        uchar_t* ep = smem;    // fp8 tile [64][stride 144]
#pragma unroll
        for (int c2 = 0; c2 < 8; ++c2) {
            int col_l = c2 * 16 + m16;
#pragma unroll
            for (int r = 0; r < 4; ++r)
                ep[(wave * 16 + quad * 4 + r) * 144 + col_l] = fp8e4m3(acc[c2][r]);
        }
        __syncthreads();
        if (g < 2) {
            // q: 128B contiguous at qb8 + gr*256 + g*128
#pragma unroll
            for (int i = 0; i < 2; ++i) {
                int ii = t + i * 256;
                int row = ii >> 3, ch = ii & 7;
                int gr = base_r + row;
                if (gr < N)
                    *(uint4*)(qb8 + (size_t)gr * 256 + g * 128 + ch * 16) =
                        *(const uint4*)(ep + row * 144 + ch * 16);
            }
        } else {
            // k (g=2,3) at chunk*16; v (g=4,5) at chunk*16+8
            const int half = (g & 1);
            const int vo = (g >= 4) ? 8 : 0;
#pragma unroll
            for (int i = 0; i < 4; ++i) {
                int ii = t + i * 256;
                int row = ii >> 4, ch = ii & 15;
                int gr = base_r + row;
                if (gr < N)
                    *(uint2*)(kvb + (size_t)gr * 512 + half * 256 + ch * 16 + vo) =
                        *(const uint2*)(ep + row * 144 + ch * 8);
            }
        }
    } else {
        // ---- 64-col skip tile, bf16 out ----
        floatx4 acc[4];
#pragma unroll
        for (int c2 = 0; c2 < 4; ++c2) acc[c2] = (floatx4){0.f, 0.f, 0.f, 0.f};
        constexpr int NU4 = (64 * C8) / 256;   // K=128: 4, K=64: 2
#pragma unroll
        for (int i = 0; i < NU4; ++i) {
            int ii = t + i * 256;
            int n = ii / C8, c = ii % C8;
            *(uint4*)(Bs + n * KP + c * 8) =
                *(const uint4*)(Wt + (size_t)(768 + n) * K + c * 8);
        }
        __syncthreads();
#pragma unroll
        for (int kc = 0; kc < K / 32; ++kc) {
            int ko = kc * 32 + quad * 8;
#pragma unroll
            for (int c2 = 0; c2 < 4; ++c2) {
                short8 b = *(const short8*)(Bs + (c2 * 16 + m16) * KP + ko);
                acc[c2] = __builtin_amdgcn_mfma_f32_16x16x32_bf16(a[kc], b, acc[c2], 0, 0, 0);
            }
        }
#pragma unroll
        for (int c2 = 0; c2 < 4; ++c2) {
            float bb = bias[768 + c2 * 16 + m16];
#pragma unroll
            for (int r = 0; r < 4; ++r) acc[c2][r] += bb;
        }
        __syncthreads();
        ushort_t* ep = (ushort_t*)smem;   // bf16 tile [64][stride 72]
#pragma unroll
        for (int c2 = 0; c2 < 4; ++c2) {
            int col_l = c2 * 16 + m16;
#pragma unroll
            for (int r = 0; r < 4; ++r)
                ep[(wave * 16 + quad * 4 + r) * 72 + col_l] = bf16rne(acc[c2][r]);
        }
        __syncthreads();
#pragma unroll
        for (int i = 0; i < 2; ++i) {
            int ii = t + i * 256;
            int row = ii >> 3, ch = ii & 7;
            int gr = base_r + row;
            if (gr < N)
                *(uint4*)(skipb + (size_t)gr * 64 + ch * 8) =
                    *(const uint4*)(ep + row * 72 + ch * 8);
        }
    }
}

// conv1 GEMM with pass-2 blocks FIRST ([0,NBUCK)): per-bucket fine scatter
// via LDS counters (zero global atomics). deg written from the counters.
template <int K>
__global__ __launch_bounds__(256) void gemm_fill12(const ushort_t* __restrict__ A,
                                                   const ushort_t* __restrict__ Wt,
                                                   const float* __restrict__ bias,
                                                   uchar_t* __restrict__ qb8,
                                                   uchar_t* __restrict__ kvb,
                                                   ushort_t* __restrict__ skipb,
                                                   int N, int RB,
                                                   const int* __restrict__ cntm,
                                                   const uint_t* __restrict__ slab,
                                                   int* __restrict__ deg,
                                                   ushort_t* __restrict__ col) {
    __shared__ uchar_t smem[(K == 128) ? 17408 : 18432] __attribute__((aligned(16)));
    int t = threadIdx.x;
    int idx = (int)blockIdx.x;
    if (idx < NBUCK) {
        __shared__ int cnt2[256];
        __shared__ int cs[P1B];
        if (t < P1B) cs[t] = cntm[idx * P1B + t];
        cnt2[t] = 0;
        __syncthreads();
        const uint_t* myslab = slab + (size_t)idx * P1B * SLABP;
        for (int i = t; i < P1B * SLABP; i += 256) {
            int blkq = i / SLABP;
            int off = i - blkq * SLABP;
            if (off < cs[blkq]) {
                uint_t rec = myslab[i];
                int d = rec >> 16;
                int pos = atomicAdd(&cnt2[d & 255], 1);
                col[((size_t)d << 6) + pos] = (ushort_t)(rec & 0xffffu);
            }
        }
        __syncthreads();
        int gn = (idx << 8) + t;
        if (gn < N_NODES) deg[gn] = cnt2[t];
        return;
    }
    gemm_body12<K>(idx - NBUCK, t, A, Wt, bias, qb8, kvb, skipb, N, RB, smem);
}

template <int K>
__global__ __launch_bounds__(256) void gemm_v12(const ushort_t* __restrict__ A,
                                                const ushort_t* __restrict__ Wt,
                                                const float* __restrict__ bias,
                                                uchar_t* __restrict__ qb8,
                                                uchar_t* __restrict__ kvb,
                                                ushort_t* __restrict__ skipb,
                                                int N, int RB) {
    __shared__ uchar_t smem[(K == 128) ? 17408 : 18432] __attribute__((aligned(16)));
    gemm_body12<K>((int)blockIdx.x, threadIdx.x, A, Wt, bias,
                   qb8, kvb, skipb, N, RB, smem);
}

// ---------------------------------------------------------------------------
// attn v8 (proven best): packed-fp32 math; q pre-scaled by 1/8; head-mean
// 0.25 folded in 1/z. kv interleaved -> ONE dwordx4 gather per lane per edge;
// adjacency list in a register (one coalesced ushort load) + shfl broadcast.
// At-roofline: 181MB compulsory L2-fill @ ~3.3 TB/s (round 6/7 evidence).
// ---------------------------------------------------------------------------
__device__ __forceinline__ void edge_step3(uint2 k8, uint2 v8, const floatx2* qp,
                                           float& z, floatx2* acp) {
    floatx2 dp = qp[0] * __builtin_amdgcn_cvt_pk_f32_fp8(k8.x, false);
    dp += qp[1] * __builtin_amdgcn_cvt_pk_f32_fp8(k8.x, true);
    dp += qp[2] * __builtin_amdgcn_cvt_pk_f32_fp8(k8.y, false);
    dp += qp[3] * __builtin_amdgcn_cvt_pk_f32_fp8(k8.y, true);
    float d = dp[0] + dp[1];
    d += __shfl_xor(d, 1);
    d += __shfl_xor(d, 2);
    d += __shfl_xor(d, 4);
    float p = __expf(d);
    z += p;
    floatx2 pp = {p, p};
    acp[0] += pp * __builtin_amdgcn_cvt_pk_f32_fp8(v8.x, false);
    acp[1] += pp * __builtin_amdgcn_cvt_pk_f32_fp8(v8.x, true);
    acp[2] += pp * __builtin_amdgcn_cvt_pk_f32_fp8(v8.y, false);
    acp[3] += pp * __builtin_amdgcn_cvt_pk_f32_fp8(v8.y, true);
}

template <bool OUT_BF16>
__global__ __launch_bounds__(256) void attn_agg7(const uchar_t* __restrict__ qb8,
                                                 const uchar_t* __restrict__ kvb,
                                                 const ushort_t* __restrict__ skipb,
                                                 const int* __restrict__ deg,
                                                 const ushort_t* __restrict__ col,
                                                 void* __restrict__ hout) {
    int node = blockIdx.x * 4 + threadIdx.y;
    if (node >= N_NODES) return;
    int lane = threadIdx.x;
    int half = lane >> 5, sl = lane & 31;
    uint2 qd = *(const uint2*)(qb8 + (size_t)node * 256 + sl * 8);
    const floatx2 s8 = {0.125f, 0.125f};
    floatx2 qp[4];
    qp[0] = s8 * __builtin_amdgcn_cvt_pk_f32_fp8(qd.x, false);
    qp[1] = s8 * __builtin_amdgcn_cvt_pk_f32_fp8(qd.x, true);
    qp[2] = s8 * __builtin_amdgcn_cvt_pk_f32_fp8(qd.y, false);
    qp[3] = s8 * __builtin_amdgcn_cvt_pk_f32_fp8(qd.y, true);
    floatx2 acp[4];
    acp[0] = (floatx2){0.f, 0.f}; acp[1] = (floatx2){0.f, 0.f};
    acp[2] = (floatx2){0.f, 0.f}; acp[3] = (floatx2){0.f, 0.f};
    float z = 0.f;
    int dv = deg[node];
    int creg = (int)col[(node << 6) | lane];  // whole adjacency row, 1 load/lane
    int e = half;
    const uchar_t* kb = kvb + (size_t)sl * 16;
    for (; e + 6 < dv; e += 8) {
        int c0 = __shfl(creg, e);
        int c1 = __shfl(creg, e + 2);
        int c2 = __shfl(creg, e + 4);
        int c3 = __shfl(creg, e + 6);
        uint4 x0 = *(const uint4*)(kb + (size_t)c0 * 512);
        uint4 x1 = *(const uint4*)(kb + (size_t)c1 * 512);
        uint4 x2 = *(const uint4*)(kb + (size_t)c2 * 512);
        uint4 x3 = *(const uint4*)(kb + (size_t)c3 * 512);
        edge_step3(make_uint2(x0.x, x0.y), make_uint2(x0.z, x0.w), qp, z, acp);
        edge_step3(make_uint2(x1.x, x1.y), make_uint2(x1.z, x1.w), qp, z, acp);
        edge_step3(make_uint2(x2.x, x2.y), make_uint2(x2.z, x2.w), qp, z, acp);
        edge_step3(make_uint2(x3.x, x3.y), make_uint2(x3.z, x3.w), qp, z, acp);
    }
    for (; e < dv; e += 2) {
        int c0 = __shfl(creg, e);
        uint4 x0 = *(const uint4*)(kb + (size_t)c0 * 512);
        edge_step3(make_uint2(x0.x, x0.y), make_uint2(x0.z, x0.w), qp, z, acp);
    }
    z += __shfl_xor(z, 32);
    float ac[8] = {acp[0][0], acp[0][1], acp[1][0], acp[1][1],
                   acp[2][0], acp[2][1], acp[3][0], acp[3][1]};
#pragma unroll
    for (int i = 0; i < 8; ++i) ac[i] += __shfl_xor(ac[i], 32);
    float inv = (z > 0.f) ? (0.25f / z) : 0.f;
#pragma unroll
    for (int i = 0; i < 8; ++i) ac[i] *= inv;
#pragma unroll
    for (int i = 0; i < 8; ++i) {
        ac[i] += __shfl_xor(ac[i], 8);
        ac[i] += __shfl_xor(ac[i], 16);
    }
    if (lane < 8) {
        uint4 su = *(const uint4*)(skipb + (size_t)node * 64 + lane * 8);
        float4 s0 = bf4_unpack(su.x, su.y);
        float4 s1 = bf4_unpack(su.z, su.w);
        float o0 = fmaxf(ac[0] + s0.x, 0.f);
        float o1 = fmaxf(ac[1] + s0.y, 0.f);
        float o2 = fmaxf(ac[2] + s0.z, 0.f);
        float o3 = fmaxf(ac[3] + s0.w, 0.f);
        float o4 = fmaxf(ac[4] + s1.x, 0.f);
        float o5 = fmaxf(ac[5] + s1.y, 0.f);
        float o6 = fmaxf(ac[6] + s1.z, 0.f);
        float o7 = fmaxf(ac[7] + s1.w, 0.f);
        if (OUT_BF16) {
            uint4 u;
            u.x = (uint_t)bf16rne(o0) | ((uint_t)bf16rne(o1) << 16);
            u.y = (uint_t)bf16rne(o2) | ((uint_t)bf16rne(o3) << 16);
            u.z = (uint_t)bf16rne(o4) | ((uint_t)bf16rne(o5) << 16);
            u.w = (uint_t)bf16rne(o6) | ((uint_t)bf16rne(o7) << 16);
            *(uint4*)((ushort_t*)hout + (size_t)node * HIDDEN + lane * 8) = u;
        } else {
            float* op = (float*)hout + (size_t)node * HIDDEN + lane * 8;
            *(float4*)(op)     = make_float4(o0, o1, o2, o3);
            *(float4*)(op + 4) = make_float4(o4, o5, o6, o7);
        }
    }
}

// ---------------------------------------------------------------------------
// fused pool + MLP head: 64 blocks x 256 threads. Each block mean-pools its
// graph's h2 rows directly (4-way chunked + LDS reduce), then k-split GEMVs.
// ---------------------------------------------------------------------------
__global__ __launch_bounds__(256) void head_mlp2(const float* __restrict__ h,
                                                 const int* __restrict__ batch,
                                                 const float* __restrict__ gf,
                                                 const float* __restrict__ gW1, const float* __restrict__ gb1,
                                                 const float* __restrict__ gW2, const float* __restrict__ gb2,
                                                 const float* __restrict__ hW1, const float* __restrict__ hb1,
                                                 const float* __restrict__ hW2, const float* __restrict__ hb2,
                                                 float* __restrict__ out) {
    int g = blockIdx.x;
    int t = threadIdx.x;
    int d = t & 63, kk = t >> 6;
    int start, end;
    graph_range(batch, g, start, end);
    float cnt = fmaxf((float)(end - start), 1.0f);
    __shared__ float gfs[GLOBAL_DIM];
    __shared__ float fused[2 * HIDDEN];
    __shared__ float g1[HIDDEN];
    __shared__ float h1s[HIDDEN];
    __shared__ float red[256];
    gfs[t] = gf[(size_t)g * GLOBAL_DIM + t];
    // ---- pool: 4 chunks x 64 dims ----
    {
        float acc = 0.f;
        for (int n = start + kk; n < end; n += 4) acc += h[(size_t)n * HIDDEN + d];
        red[t] = acc;
        __syncthreads();
        if (t < 64)
            fused[t] = (red[t] + red[64 + t] + red[128 + t] + red[192 + t]) / cnt;
        __syncthreads();
    }
    {
        float a = 0.f;
        int k0 = kk * 64;
#pragma unroll 4
        for (int k = k0; k < k0 + 64; ++k) a = fmaf(gfs[k], gW1[k * HIDDEN + d], a);
        red[t] = a;
        __syncthreads();
        if (t < 64) g1[t] = fmaxf(red[t] + red[64 + t] + red[128 + t] + red[192 + t] + gb1[t], 0.f);
        __syncthreads();
    }
    {
        float a = 0.f;
        int k0 = kk * 16;
#pragma unroll 4
        for (int k = k0; k < k0 + 16; ++k) a = fmaf(g1[k], gW2[k * HIDDEN + d], a);
        red[t] = a;
        __syncthreads();
        if (t < 64) fused[HIDDEN + t] =
            fmaxf(red[t] + red[64 + t] + red[128 + t] + red[192 + t] + gb2[t], 0.f);
        __syncthreads();
    }
    {
        float a = 0.f;
        int k0 = kk * 32;
#pragma unroll 4
        for (int k = k0; k < k0 + 32; ++k) a = fmaf(fused[k], hW1[k * HIDDEN + d], a);
        red[t] = a;
        __syncthreads();
        if (t < 64) h1s[t] = fmaxf(red[t] + red[64 + t] + red[128 + t] + red[192 + t] + hb1[t], 0.f);
        __syncthreads();
    }
    if (t < N_CLASSES) {
        float o = hb2[t];
#pragma unroll 4
        for (int k = 0; k < HIDDEN; ++k) o = fmaf(h1s[k], hW2[k * N_CLASSES + t], o);
        out[(size_t)g * N_CLASSES + t] = o;
    }
}

// ---------------------------------------------------------------------------
extern "C" void kernel_launch(void* const* d_in, const int* in_sizes, int n_in,
                              void* d_out, int out_size, void* d_ws, size_t ws_size,
                              hipStream_t stream) {
    const float* x        = (const float*)d_in[0];
    const int*   eidx     = (const int*)d_in[1];
    const int*   batch    = (const int*)d_in[2];
    const float* gfeats   = (const float*)d_in[3];
    const float* c1_Wq = (const float*)d_in[4];  const float* c1_bq = (const float*)d_in[5];
    const float* c1_Wk = (const float*)d_in[6];  const float* c1_bk = (const float*)d_in[7];
    const float* c1_Wv = (const float*)d_in[8];  const float* c1_bv = (const float*)d_in[9];
    const float* c1_Ws = (const float*)d_in[10]; const float* c1_bs = (const float*)d_in[11];
    const float* c2_Wq = (const float*)d_in[12]; const float* c2_bq = (const float*)d_in[13];
    const float* c2_Wk = (const float*)d_in[14]; const float* c2_bk = (const float*)d_in[15];
    const float* c2_Wv = (const float*)d_in[16]; const float* c2_bv = (const float*)d_in[17];
    const float* c2_Ws = (const float*)d_in[18]; const float* c2_bs = (const float*)d_in[19];
    const float* g_W1 = (const float*)d_in[20]; const float* g_b1 = (const float*)d_in[21];
    const float* g_W2 = (const float*)d_in[22]; const float* g_b2 = (const float*)d_in[23];
    const float* h_W1 = (const float*)d_in[24]; const float* h_b1 = (const float*)d_in[25];
    const float* h_W2 = (const float*)d_in[26]; const float* h_b2 = (const float*)d_in[27];
    float* out = (float*)d_out;

    const int* srcp = eidx;
    const int* dstp = eidx + N_EDGES;

    // ---- workspace layout (~84 MB; slab/cntm alias h2) ----
    char* base = (char*)d_ws;
    uchar_t*  kvb  = (uchar_t*)base;  base += (size_t)N_NODES * 512;
    uchar_t*  qb8  = (uchar_t*)base;  base += (size_t)N_NODES * 256;
    ushort_t* skipb = (ushort_t*)base; base += (size_t)N_NODES * HIDDEN * 2;
    ushort_t* h1b  = (ushort_t*)base; base += (size_t)N_NODES * HIDDEN * 2;
    float*    h2   = (float*)base;    base += (size_t)N_NODES * HIDDEN * 4;
    ushort_t* Wt1  = (ushort_t*)base; base += (size_t)IN_CH * QKV_COLS * 2;
    ushort_t* Wt2  = (ushort_t*)base; base += (size_t)HIDDEN * QKV_COLS * 2;
    float*    bcat1 = (float*)base;   base += QKV_COLS * 4;
    float*    bcat2 = (float*)base;   base += QKV_COLS * 4;
    int*      deg  = (int*)base;      base += (size_t)N_NODES * 4;
    ushort_t* colb = (ushort_t*)base; base += ((size_t)N_NODES * MAXDEG + 64) * 2;
    ushort_t* xb   = (ushort_t*)base; base += (size_t)N_NODES * IN_CH * 2;  // bf16 x

    // slab (9.63MB) + cntm (0.2MB) alias h2 (12.8MB): dead before attn2
    // writes h2 (stream-ordered).
    uint_t* slab = (uint_t*)h2;
    int*    cntm = (int*)((char*)h2 + (size_t)NBUCK * P1B * SLABP * 4);

    const int RB = (N_NODES + 63) / 64;        // 782
    const int GG = 8 * 7 * ((RB + 7) / 8);     // 5488
    dim3 attn_block(64, 4);
    int attn_grid = (N_NODES + 3) / 4;         // 12500

    // ---- prep: weight concat || pass-1 bucket scatter || x->bf16 ----
    prep_p1<<<PREP_CONC_B + P1B + XCB, 256, 0, stream>>>(
        c1_Wq, c1_Wk, c1_Wv, c1_Ws, c1_bq, c1_bk, c1_bv, c1_bs,
        c2_Wq, c2_Wk, c2_Wv, c2_Ws, c2_bq, c2_bk, c2_bv, c2_bs,
        Wt1, Wt2, bcat1, bcat2, srcp, dstp, slab, cntm, x, xb);

    // ---- conv1 GEMM || pass-2 fine scatter (pass-2 blocks FIRST) ----
    gemm_fill12<IN_CH><<<NBUCK + GG, 256, 0, stream>>>(
        xb, Wt1, bcat1, qb8, kvb, skipb, N_NODES, RB, cntm, slab, deg, colb);
    attn_agg7<true><<<attn_grid, attn_block, 0, stream>>>(qb8, kvb, skipb, deg, colb, h1b);

    // ---- conv2 (A = h1b bf16) ----
    gemm_v12<HIDDEN><<<GG, 256, 0, stream>>>(h1b, Wt2, bcat2, qb8, kvb, skipb, N_NODES, RB);
    attn_agg7<false><<<attn_grid, attn_block, 0, stream>>>(qb8, kvb, skipb, deg, colb, h2);

    // ---- fused pool + head ----
    head_mlp2<<<N_GRAPHS, 256, 0, stream>>>(h2, batch, gfeats,
                                            g_W1, g_b1, g_W2, g_b2,
                                            h_W1, h_b1, h_W2, h_b2, out);
}

// Round 9
// 329.602 us; speedup vs baseline: 1.0952x; 1.0952x over previous
//
#include <hip/hip_runtime.h>
#include <hip/hip_bf16.h>
#include <math.h>

#define N_NODES   50000
#define N_EDGES   800000
#define N_GRAPHS  64
#define IN_CH     128
#define GLOBAL_DIM 256
#define HIDDEN    64
#define HEADS     4
#define N_CLASSES 10
#define QKV_COLS  832   // 256 q | 256 k | 256 v | 64 skip
#define MAXDEG    64

// bucket scatter (atomic-free CSR build)
#define P1B    256      // pass-1 blocks
#define EPB    3125     // edges per pass-1 block (256*3125 = 800000 exact)
#define NBUCK  196      // ceil(50000/256) buckets of 256 nodes
#define SLABP  48       // slots per (bucket,block): mean 15.9, sd 4.0 -> 8sigma

// x -> bf16 conversion blocks in prep
#define XCB    3125     // 3125 * 256 * 8 = 6.4M elements exact

typedef unsigned short ushort_t;
typedef unsigned int uint_t;
typedef unsigned char uchar_t;
typedef __attribute__((ext_vector_type(8))) short short8;
typedef __attribute__((ext_vector_type(4))) float floatx4;
typedef __attribute__((ext_vector_type(2))) float floatx2;

// ---------------------------------------------------------------------------
// helpers
// ---------------------------------------------------------------------------
__device__ __forceinline__ ushort_t bf16rne(float f) {
    uint_t b = __float_as_uint(f);
    b += 0x7fffu + ((b >> 16) & 1u);
    return (ushort_t)(b >> 16);
}
__device__ __forceinline__ float4 bf4_unpack(uint_t lo, uint_t hi) {
    float4 f;
    f.x = __uint_as_float(lo << 16);
    f.y = __uint_as_float(lo & 0xffff0000u);
    f.z = __uint_as_float(hi << 16);
    f.w = __uint_as_float(hi & 0xffff0000u);
    return f;
}
__device__ __forceinline__ uchar_t fp8e4m3(float f) {
    int v = __builtin_amdgcn_cvt_pk_fp8_f32(f, 0.f, 0, false);
    return (uchar_t)(v & 0xff);
}
__device__ __forceinline__ short8 pack_bf8(float4 a, float4 b) {
    union { short8 s; ushort_t u[8]; } r;
    r.u[0] = bf16rne(a.x); r.u[1] = bf16rne(a.y);
    r.u[2] = bf16rne(a.z); r.u[3] = bf16rne(a.w);
    r.u[4] = bf16rne(b.x); r.u[5] = bf16rne(b.y);
    r.u[6] = bf16rne(b.z); r.u[7] = bf16rne(b.w);
    return r.s;
}
__device__ __forceinline__ void graph_range(const int* __restrict__ batch, int g,
                                            int& start, int& end) {
    int lo = 0, hi = N_NODES;
    while (lo < hi) { int mid = (lo + hi) >> 1; if (batch[mid] < g) lo = mid + 1; else hi = mid; }
    start = lo;
    hi = N_NODES;
    while (lo < hi) { int mid = (lo + hi) >> 1; if (batch[mid] < g + 1) lo = mid + 1; else hi = mid; }
    end = lo;
}

// ---------------------------------------------------------------------------
// PREP: weight concat [0,624) || pass-1 bucket scatter [624,880) ||
//       x fp32->bf16 conversion [880, 880+3125)
// ---------------------------------------------------------------------------
#define PREP_CONC_B  624

__global__ __launch_bounds__(256) void prep_p1(
        const float* __restrict__ W1q, const float* __restrict__ W1k,
        const float* __restrict__ W1v, const float* __restrict__ W1s,
        const float* __restrict__ b1q, const float* __restrict__ b1k,
        const float* __restrict__ b1v, const float* __restrict__ b1s,
        const float* __restrict__ W2q, const float* __restrict__ W2k,
        const float* __restrict__ W2v, const float* __restrict__ W2s,
        const float* __restrict__ b2q, const float* __restrict__ b2k,
        const float* __restrict__ b2v, const float* __restrict__ b2s,
        ushort_t* __restrict__ Wt1, ushort_t* __restrict__ Wt2,
        float* __restrict__ bcat1, float* __restrict__ bcat2,
        const int* __restrict__ src, const int* __restrict__ dst,
        uint_t* __restrict__ slab, int* __restrict__ cntm,
        const float* __restrict__ x, ushort_t* __restrict__ xb) {
    int b = blockIdx.x, t = threadIdx.x;
    if (b >= PREP_CONC_B + P1B) {
        // ---- x conversion: 8 floats per thread ----
        int base = (b - (PREP_CONC_B + P1B)) * 2048 + t * 8;
        float4 f0 = *(const float4*)(x + base);
        float4 f1 = *(const float4*)(x + base + 4);
        *(short8*)(xb + base) = pack_bf8(f0, f1);
        return;
    }
    if (b >= PREP_CONC_B) {
        int blk = b - PREP_CONC_B;
        __shared__ int hist[NBUCK];
        for (int i = t; i < NBUCK; i += 256) hist[i] = 0;
        __syncthreads();
        int e0 = blk * EPB;
        int e1 = e0 + EPB;
        for (int e = e0 + t; e < e1; e += 256) {
            int s = src[e], d = dst[e];
            int bu = d >> 8;
            int off = atomicAdd(&hist[bu], 1);
            if (off < SLABP)
                slab[((size_t)bu * P1B + blk) * SLABP + off] =
                    ((uint_t)d << 16) | (uint_t)s;
        }
        __syncthreads();
        for (int i = t; i < NBUCK; i += 256)
            cntm[i * P1B + blk] = hist[i] < SLABP ? hist[i] : SLABP;
        return;
    }
    int idx = b * 256 + t;
    const int T1 = IN_CH * QKV_COLS;
    const int T2 = HIDDEN * QKV_COLS;
    if (idx < T1) {
        int c = idx / IN_CH, k = idx % IN_CH;
        float v;
        if (c < 256)      v = W1q[k * 256 + c];
        else if (c < 512) v = W1k[k * 256 + (c - 256)];
        else if (c < 768) v = W1v[k * 256 + (c - 512)];
        else              v = W1s[k * 64  + (c - 768)];
        Wt1[idx] = bf16rne(v);
    } else if (idx < T1 + T2) {
        int i2 = idx - T1;
        int c = i2 / HIDDEN, k = i2 % HIDDEN;
        float v;
        if (c < 256)      v = W2q[k * 256 + c];
        else if (c < 512) v = W2k[k * 256 + (c - 256)];
        else if (c < 768) v = W2v[k * 256 + (c - 512)];
        else              v = W2s[k * 64  + (c - 768)];
        Wt2[i2] = bf16rne(v);
    }
    if (idx < QKV_COLS) {
        float bb, b2;
        if (idx < 256)      { bb = b1q[idx];       b2 = b2q[idx]; }
        else if (idx < 512) { bb = b1k[idx - 256]; b2 = b2k[idx - 256]; }
        else if (idx < 768) { bb = b1v[idx - 512]; b2 = b2v[idx - 512]; }
        else                { bb = b1s[idx - 768]; b2 = b2s[idx - 768]; }
        bcat1[idx] = bb;
        bcat2[idx] = b2;
    }
}

// ---------------------------------------------------------------------------
// GEMM v12 body: 64-row strips, 1 row-tile per wave (acc 32 VGPR), A always
// bf16 (xb for conv1). 7 groups: g 0-5 = 128-col qkv tiles, g6 = 64-col skip.
// K=128: two-stage B (64 cols each, LDS 17.4KB). K=64: single-stage (18.4KB).
// kv interleave: chunk i (16B) = k[8i..8i+7] || v[8i..8i+7].
// ---------------------------------------------------------------------------
template <int K>
__device__ __forceinline__ void gemm_body12(int idx0, int t,
                                            const ushort_t* __restrict__ A,
                                            const ushort_t* __restrict__ Wt,
                                            const float* __restrict__ bias,
                                            uchar_t* __restrict__ qb8,
                                            uchar_t* __restrict__ kvb,
                                            ushort_t* __restrict__ skipb,
                                            int N, int RB, uchar_t* smem) {
    constexpr int KP = K + 8;
    constexpr int C8 = K / 8;
    ushort_t* Bs = (ushort_t*)smem;

    const int xcd = idx0 & 7;
    const int j = idx0 >> 3;
    const int g = j % 7;
    const int strip = (j / 7) * 8 + xcd;
    if (strip >= RB) return;
    const int base_r = strip * 64;

    const int wave = t >> 6, lane = t & 63;
    const int quad = lane >> 4, m16 = lane & 15;

    // A fragments: wave handles rows base_r + wave*16 .. +15; once per block.
    int arow = base_r + wave * 16 + m16;
    int cr = arow < N ? arow : N - 1;
    const ushort_t* Ar = A + (size_t)cr * K + quad * 8;
    short8 a[K / 32];
#pragma unroll
    for (int kc = 0; kc < K / 32; ++kc) a[kc] = *(const short8*)(Ar + kc * 32);

    if (g < 6) {
        const int base_c = g * 128;
        floatx4 acc[8];
#pragma unroll
        for (int c2 = 0; c2 < 8; ++c2) acc[c2] = (floatx4){0.f, 0.f, 0.f, 0.f};

        if (K == 128) {
            // two-stage: 64 cols per stage, Bs reused
#pragma unroll
            for (int hc = 0; hc < 2; ++hc) {
                if (hc) __syncthreads();   // all waves done with half 0
#pragma unroll
                for (int i = 0; i < 4; ++i) {
                    int ii = t + i * 256;
                    int n = ii / C8, c = ii % C8;
                    *(uint4*)(Bs + n * KP + c * 8) =
                        *(const uint4*)(Wt + (size_t)(base_c + hc * 64 + n) * K + c * 8);
                }
                __syncthreads();
#pragma unroll
                for (int kc = 0; kc < K / 32; ++kc) {
                    int ko = kc * 32 + quad * 8;
#pragma unroll
                    for (int c2 = 0; c2 < 4; ++c2) {
                        short8 b = *(const short8*)(Bs + (c2 * 16 + m16) * KP + ko);
                        acc[hc * 4 + c2] =
                            __builtin_amdgcn_mfma_f32_16x16x32_bf16(a[kc], b, acc[hc * 4 + c2], 0, 0, 0);
                    }
                }
            }
        } else {
            // single-stage: all 128 cols
#pragma unroll
            for (int i = 0; i < 4; ++i) {
                int ii = t + i * 256;
                int n = ii / C8, c = ii % C8;
                *(uint4*)(Bs + n * KP + c * 8) =
                    *(const uint4*)(Wt + (size_t)(base_c + n) * K + c * 8);
            }
            __syncthreads();
#pragma unroll
            for (int kc = 0; kc < K / 32; ++kc) {
                int ko = kc * 32 + quad * 8;
#pragma unroll
                for (int c2 = 0; c2 < 8; ++c2) {
                    short8 b = *(const short8*)(Bs + (c2 * 16 + m16) * KP + ko);
                    acc[c2] = __builtin_amdgcn_mfma_f32_16x16x32_bf16(a[kc], b, acc[c2], 0, 0, 0);
                }
            }
        }

#pragma unroll
        for (int c2 = 0; c2 < 8; ++c2) {
            float bb = bias[base_c + c2 * 16 + m16];
#pragma unroll
            for (int r = 0; r < 4; ++r) acc[c2][r] += bb;
        }

        __syncthreads();   // Bs free -> epilogue tile
        uchar_t* ep = smem;    // fp8 tile [64][stride 144]
#pragma unroll
        for (int c2 = 0; c2 < 8; ++c2) {
            int col_l = c2 * 16 + m16;
#pragma unroll
            for (int r = 0; r < 4; ++r)
                ep[(wave * 16 + quad * 4 + r) * 144 + col_l] = fp8e4m3(acc[c2][r]);
        }
        __syncthreads();
        if (g < 2) {
            // q: 128B contiguous at qb8 + gr*256 + g*128
#pragma unroll
            for (int i = 0; i < 2; ++i) {
                int ii = t + i * 256;
                int row = ii >> 3, ch = ii & 7;
                int gr = base_r + row;
                if (gr < N)
                    *(uint4*)(qb8 + (size_t)gr * 256 + g * 128 + ch * 16) =
                        *(const uint4*)(ep + row * 144 + ch * 16);
            }
        } else {
            // k (g=2,3) at chunk*16; v (g=4,5) at chunk*16+8
            const int half = (g & 1);
            const int vo = (g >= 4) ? 8 : 0;
#pragma unroll
            for (int i = 0; i < 4; ++i) {
                int ii = t + i * 256;
                int row = ii >> 4, ch = ii & 15;
                int gr = base_r + row;
                if (gr < N)
                    *(uint2*)(kvb + (size_t)gr * 512 + half * 256 + ch * 16 + vo) =
                        *(const uint2*)(ep + row * 144 + ch * 8);
            }
        }
    } else {
        // ---- 64-col skip tile, bf16 out ----
        floatx4 acc[4];
#pragma unroll
        for (int c2 = 0; c2 < 4; ++c2) acc[c2] = (floatx4){0.f, 0.f, 0.f, 0.f};
        constexpr int NU4 = (64 * C8) / 256;   // K=128: 4, K=64: 2
#pragma unroll
        for (int i = 0; i < NU4; ++i) {
            int ii = t + i * 256;
            int n = ii / C8, c = ii % C8;
            *(uint4*)(Bs + n * KP + c * 8) =
                *(const uint4*)(Wt + (size_t)(768 + n) * K + c * 8);
        }
        __syncthreads();
#pragma unroll
        for (int kc = 0; kc < K / 32; ++kc) {
            int ko = kc * 32 + quad * 8;
#pragma unroll
            for (int c2 = 0; c2 < 4; ++c2) {
                short8 b = *(const short8*)(Bs + (c2 * 16 + m16) * KP + ko);
                acc[c2] = __builtin_amdgcn_mfma_f32_16x16x32_bf16(a[kc], b, acc[c2], 0, 0, 0);
            }
        }
#pragma unroll
        for (int c2 = 0; c2 < 4; ++c2) {
            float bb = bias[768 + c2 * 16 + m16];
#pragma unroll
            for (int r = 0; r < 4; ++r) acc[c2][r] += bb;
        }
        __syncthreads();
        ushort_t* ep = (ushort_t*)smem;   // bf16 tile [64][stride 72]
#pragma unroll
        for (int c2 = 0; c2 < 4; ++c2) {
            int col_l = c2 * 16 + m16;
#pragma unroll
            for (int r = 0; r < 4; ++r)
                ep[(wave * 16 + quad * 4 + r) * 72 + col_l] = bf16rne(acc[c2][r]);
        }
        __syncthreads();
#pragma unroll
        for (int i = 0; i < 2; ++i) {
            int ii = t + i * 256;
            int row = ii >> 3, ch = ii & 7;
            int gr = base_r + row;
            if (gr < N)
                *(uint4*)(skipb + (size_t)gr * 64 + ch * 8) =
                    *(const uint4*)(ep + row * 72 + ch * 8);
        }
    }
}

// conv1 GEMM with pass-2 blocks FIRST ([0,NBUCK)): per-bucket fine scatter
// via LDS counters (zero global atomics). deg written from the counters.
template <int K>
__global__ __launch_bounds__(256) void gemm_fill12(const ushort_t* __restrict__ A,
                                                   const ushort_t* __restrict__ Wt,
                                                   const float* __restrict__ bias,
                                                   uchar_t* __restrict__ qb8,
                                                   uchar_t* __restrict__ kvb,
                                                   ushort_t* __restrict__ skipb,
                                                   int N, int RB,
                                                   const int* __restrict__ cntm,
                                                   const uint_t* __restrict__ slab,
                                                   int* __restrict__ deg,
                                                   ushort_t* __restrict__ col) {
    __shared__ uchar_t smem[(K == 128) ? 17408 : 18432] __attribute__((aligned(16)));
    int t = threadIdx.x;
    int idx = (int)blockIdx.x;
    if (idx < NBUCK) {
        __shared__ int cnt2[256];
        __shared__ int cs[P1B];
        if (t < P1B) cs[t] = cntm[idx * P1B + t];
        cnt2[t] = 0;
        __syncthreads();
        const uint_t* myslab = slab + (size_t)idx * P1B * SLABP;
        for (int i = t; i < P1B * SLABP; i += 256) {
            int blkq = i / SLABP;
            int off = i - blkq * SLABP;
            if (off < cs[blkq]) {
                uint_t rec = myslab[i];
                int d = rec >> 16;
                int pos = atomicAdd(&cnt2[d & 255], 1);
                col[((size_t)d << 6) + pos] = (ushort_t)(rec & 0xffffu);
            }
        }
        __syncthreads();
        int gn = (idx << 8) + t;
        if (gn < N_NODES) deg[gn] = cnt2[t];
        return;
    }
    gemm_body12<K>(idx - NBUCK, t, A, Wt, bias, qb8, kvb, skipb, N, RB, smem);
}

template <int K>
__global__ __launch_bounds__(256) void gemm_v12(const ushort_t* __restrict__ A,
                                                const ushort_t* __restrict__ Wt,
                                                const float* __restrict__ bias,
                                                uchar_t* __restrict__ qb8,
                                                uchar_t* __restrict__ kvb,
                                                ushort_t* __restrict__ skipb,
                                                int N, int RB) {
    __shared__ uchar_t smem[(K == 128) ? 17408 : 18432] __attribute__((aligned(16)));
    gemm_body12<K>((int)blockIdx.x, threadIdx.x, A, Wt, bias,
                   qb8, kvb, skipb, N, RB, smem);
}

// ---------------------------------------------------------------------------
// attn v8 (proven best): packed-fp32 math; q pre-scaled by 1/8; head-mean
// 0.25 folded in 1/z. kv interleaved -> ONE dwordx4 gather per lane per edge;
// adjacency list in a register (one coalesced ushort load) + shfl broadcast.
// At-roofline: 181MB compulsory L2-fill @ ~3.3 TB/s (round 6/7 evidence).
// ---------------------------------------------------------------------------
__device__ __forceinline__ void edge_step3(uint2 k8, uint2 v8, const floatx2* qp,
                                           float& z, floatx2* acp) {
    floatx2 dp = qp[0] * __builtin_amdgcn_cvt_pk_f32_fp8(k8.x, false);
    dp += qp[1] * __builtin_amdgcn_cvt_pk_f32_fp8(k8.x, true);
    dp += qp[2] * __builtin_amdgcn_cvt_pk_f32_fp8(k8.y, false);
    dp += qp[3] * __builtin_amdgcn_cvt_pk_f32_fp8(k8.y, true);
    float d = dp[0] + dp[1];
    d += __shfl_xor(d, 1);
    d += __shfl_xor(d, 2);
    d += __shfl_xor(d, 4);
    float p = __expf(d);
    z += p;
    floatx2 pp = {p, p};
    acp[0] += pp * __builtin_amdgcn_cvt_pk_f32_fp8(v8.x, false);
    acp[1] += pp * __builtin_amdgcn_cvt_pk_f32_fp8(v8.x, true);
    acp[2] += pp * __builtin_amdgcn_cvt_pk_f32_fp8(v8.y, false);
    acp[3] += pp * __builtin_amdgcn_cvt_pk_f32_fp8(v8.y, true);
}

template <bool OUT_BF16>
__global__ __launch_bounds__(256) void attn_agg7(const uchar_t* __restrict__ qb8,
                                                 const uchar_t* __restrict__ kvb,
                                                 const ushort_t* __restrict__ skipb,
                                                 const int* __restrict__ deg,
                                                 const ushort_t* __restrict__ col,
                                                 void* __restrict__ hout) {
    int node = blockIdx.x * 4 + threadIdx.y;
    if (node >= N_NODES) return;
    int lane = threadIdx.x;
    int half = lane >> 5, sl = lane & 31;
    uint2 qd = *(const uint2*)(qb8 + (size_t)node * 256 + sl * 8);
    const floatx2 s8 = {0.125f, 0.125f};
    floatx2 qp[4];
    qp[0] = s8 * __builtin_amdgcn_cvt_pk_f32_fp8(qd.x, false);
    qp[1] = s8 * __builtin_amdgcn_cvt_pk_f32_fp8(qd.x, true);
    qp[2] = s8 * __builtin_amdgcn_cvt_pk_f32_fp8(qd.y, false);
    qp[3] = s8 * __builtin_amdgcn_cvt_pk_f32_fp8(qd.y, true);
    floatx2 acp[4];
    acp[0] = (floatx2){0.f, 0.f}; acp[1] = (floatx2){0.f, 0.f};
    acp[2] = (floatx2){0.f, 0.f}; acp[3] = (floatx2){0.f, 0.f};
    float z = 0.f;
    int dv = deg[node];
    int creg = (int)col[(node << 6) | lane];  // whole adjacency row, 1 load/lane
    int e = half;
    const uchar_t* kb = kvb + (size_t)sl * 16;
    for (; e + 6 < dv; e += 8) {
        int c0 = __shfl(creg, e);
        int c1 = __shfl(creg, e + 2);
        int c2 = __shfl(creg, e + 4);
        int c3 = __shfl(creg, e + 6);
        uint4 x0 = *(const uint4*)(kb + (size_t)c0 * 512);
        uint4 x1 = *(const uint4*)(kb + (size_t)c1 * 512);
        uint4 x2 = *(const uint4*)(kb + (size_t)c2 * 512);
        uint4 x3 = *(const uint4*)(kb + (size_t)c3 * 512);
        edge_step3(make_uint2(x0.x, x0.y), make_uint2(x0.z, x0.w), qp, z, acp);
        edge_step3(make_uint2(x1.x, x1.y), make_uint2(x1.z, x1.w), qp, z, acp);
        edge_step3(make_uint2(x2.x, x2.y), make_uint2(x2.z, x2.w), qp, z, acp);
        edge_step3(make_uint2(x3.x, x3.y), make_uint2(x3.z, x3.w), qp, z, acp);
    }
    for (; e < dv; e += 2) {
        int c0 = __shfl(creg, e);
        uint4 x0 = *(const uint4*)(kb + (size_t)c0 * 512);
        edge_step3(make_uint2(x0.x, x0.y), make_uint2(x0.z, x0.w), qp, z, acp);
    }
    z += __shfl_xor(z, 32);
    float ac[8] = {acp[0][0], acp[0][1], acp[1][0], acp[1][1],
                   acp[2][0], acp[2][1], acp[3][0], acp[3][1]};
#pragma unroll
    for (int i = 0; i < 8; ++i) ac[i] += __shfl_xor(ac[i], 32);
    float inv = (z > 0.f) ? (0.25f / z) : 0.f;
#pragma unroll
    for (int i = 0; i < 8; ++i) ac[i] *= inv;
#pragma unroll
    for (int i = 0; i < 8; ++i) {
        ac[i] += __shfl_xor(ac[i], 8);
        ac[i] += __shfl_xor(ac[i], 16);
    }
    if (lane < 8) {
        uint4 su = *(const uint4*)(skipb + (size_t)node * 64 + lane * 8);
        float4 s0 = bf4_unpack(su.x, su.y);
        float4 s1 = bf4_unpack(su.z, su.w);
        float o0 = fmaxf(ac[0] + s0.x, 0.f);
        float o1 = fmaxf(ac[1] + s0.y, 0.f);
        float o2 = fmaxf(ac[2] + s0.z, 0.f);
        float o3 = fmaxf(ac[3] + s0.w, 0.f);
        float o4 = fmaxf(ac[4] + s1.x, 0.f);
        float o5 = fmaxf(ac[5] + s1.y, 0.f);
        float o6 = fmaxf(ac[6] + s1.z, 0.f);
        float o7 = fmaxf(ac[7] + s1.w, 0.f);
        if (OUT_BF16) {
            uint4 u;
            u.x = (uint_t)bf16rne(o0) | ((uint_t)bf16rne(o1) << 16);
            u.y = (uint_t)bf16rne(o2) | ((uint_t)bf16rne(o3) << 16);
            u.z = (uint_t)bf16rne(o4) | ((uint_t)bf16rne(o5) << 16);
            u.w = (uint_t)bf16rne(o6) | ((uint_t)bf16rne(o7) << 16);
            *(uint4*)((ushort_t*)hout + (size_t)node * HIDDEN + lane * 8) = u;
        } else {
            float* op = (float*)hout + (size_t)node * HIDDEN + lane * 8;
            *(float4*)(op)     = make_float4(o0, o1, o2, o3);
            *(float4*)(op + 4) = make_float4(o4, o5, o6, o7);
        }
    }
}

// ---------------------------------------------------------------------------
// pool phase A: 512 blocks = (graph, slice of 8). part[(g*8+s)*64 + d].
// ---------------------------------------------------------------------------
__global__ __launch_bounds__(256) void pool_partial(const float* __restrict__ h,
                                                    const int* __restrict__ batch,
                                                    float* __restrict__ part) {
    int g = blockIdx.x >> 3;
    int s = blockIdx.x & 7;
    int start, end;
    graph_range(batch, g, start, end);
    int len = end - start;
    int s0 = start + (len * s) / 8;
    int s1 = start + (len * (s + 1)) / 8;
    int t = threadIdx.x;
    int d = t & 63, chunk = t >> 6;
    float acc = 0.f;
    for (int n = s0 + chunk; n < s1; n += 4) acc += h[(size_t)n * HIDDEN + d];
    __shared__ float sh[256];
    sh[t] = acc;
    __syncthreads();
    if (t < 64)
        part[(size_t)blockIdx.x * 64 + t] = sh[t] + sh[64 + t] + sh[128 + t] + sh[192 + t];
}

// ---------------------------------------------------------------------------
// pool phase B + MLP head: 64 blocks x 256 threads, k-split GEMV layers.
// ---------------------------------------------------------------------------
__global__ __launch_bounds__(256) void head_mlp(const float* __restrict__ part,
                                                const int* __restrict__ batch,
                                                const float* __restrict__ gf,
                                                const float* __restrict__ gW1, const float* __restrict__ gb1,
                                                const float* __restrict__ gW2, const float* __restrict__ gb2,
                                                const float* __restrict__ hW1, const float* __restrict__ hb1,
                                                const float* __restrict__ hW2, const float* __restrict__ hb2,
                                                float* __restrict__ out) {
    int g = blockIdx.x;
    int t = threadIdx.x;
    int d = t & 63, kk = t >> 6;
    int start, end;
    graph_range(batch, g, start, end);
    float cnt = fmaxf((float)(end - start), 1.0f);
    __shared__ float gfs[GLOBAL_DIM];
    __shared__ float fused[2 * HIDDEN];
    __shared__ float g1[HIDDEN];
    __shared__ float h1s[HIDDEN];
    __shared__ float red[256];
    gfs[t] = gf[(size_t)g * GLOBAL_DIM + t];
    if (t < 64) {
        float s = 0.f;
#pragma unroll
        for (int i = 0; i < 8; ++i) s += part[((size_t)g * 8 + i) * 64 + t];
        fused[t] = s / cnt;
    }
    __syncthreads();
    {
        float a = 0.f;
        int k0 = kk * 64;
#pragma unroll 4
        for (int k = k0; k < k0 + 64; ++k) a = fmaf(gfs[k], gW1[k * HIDDEN + d], a);
        red[t] = a;
        __syncthreads();
        if (t < 64) g1[t] = fmaxf(red[t] + red[64 + t] + red[128 + t] + red[192 + t] + gb1[t], 0.f);
        __syncthreads();
    }
    {
        float a = 0.f;
        int k0 = kk * 16;
#pragma unroll 4
        for (int k = k0; k < k0 + 16; ++k) a = fmaf(g1[k], gW2[k * HIDDEN + d], a);
        red[t] = a;
        __syncthreads();
        if (t < 64) fused[HIDDEN + t] =
            fmaxf(red[t] + red[64 + t] + red[128 + t] + red[192 + t] + gb2[t], 0.f);
        __syncthreads();
    }
    {
        float a = 0.f;
        int k0 = kk * 32;
#pragma unroll 4
        for (int k = k0; k < k0 + 32; ++k) a = fmaf(fused[k], hW1[k * HIDDEN + d], a);
        red[t] = a;
        __syncthreads();
        if (t < 64) h1s[t] = fmaxf(red[t] + red[64 + t] + red[128 + t] + red[192 + t] + hb1[t], 0.f);
        __syncthreads();
    }
    if (t < N_CLASSES) {
        float o = hb2[t];
#pragma unroll 4
        for (int k = 0; k < HIDDEN; ++k) o = fmaf(h1s[k], hW2[k * N_CLASSES + t], o);
        out[(size_t)g * N_CLASSES + t] = o;
    }
}

// ---------------------------------------------------------------------------
extern "C" void kernel_launch(void* const* d_in, const int* in_sizes, int n_in,
                              void* d_out, int out_size, void* d_ws, size_t ws_size,
                              hipStream_t stream) {
    const float* x        = (const float*)d_in[0];
    const int*   eidx     = (const int*)d_in[1];
    const int*   batch    = (const int*)d_in[2];
    const float* gfeats   = (const float*)d_in[3];
    const float* c1_Wq = (const float*)d_in[4];  const float* c1_bq = (const float*)d_in[5];
    const float* c1_Wk = (const float*)d_in[6];  const float* c1_bk = (const float*)d_in[7];
    const float* c1_Wv = (const float*)d_in[8];  const float* c1_bv = (const float*)d_in[9];
    const float* c1_Ws = (const float*)d_in[10]; const float* c1_bs = (const float*)d_in[11];
    const float* c2_Wq = (const float*)d_in[12]; const float* c2_bq = (const float*)d_in[13];
    const float* c2_Wk = (const float*)d_in[14]; const float* c2_bk = (const float*)d_in[15];
    const float* c2_Wv = (const float*)d_in[16]; const float* c2_bv = (const float*)d_in[17];
    const float* c2_Ws = (const float*)d_in[18]; const float* c2_bs = (const float*)d_in[19];
    const float* g_W1 = (const float*)d_in[20]; const float* g_b1 = (const float*)d_in[21];
    const float* g_W2 = (const float*)d_in[22]; const float* g_b2 = (const float*)d_in[23];
    const float* h_W1 = (const float*)d_in[24]; const float* h_b1 = (const float*)d_in[25];
    const float* h_W2 = (const float*)d_in[26]; const float* h_b2 = (const float*)d_in[27];
    float* out = (float*)d_out;

    const int* srcp = eidx;
    const int* dstp = eidx + N_EDGES;

    // ---- workspace layout (~84 MB; slab/cntm alias h2) ----
    char* base = (char*)d_ws;
    uchar_t*  kvb  = (uchar_t*)base;  base += (size_t)N_NODES * 512;
    uchar_t*  qb8  = (uchar_t*)base;  base += (size_t)N_NODES * 256;
    ushort_t* skipb = (ushort_t*)base; base += (size_t)N_NODES * HIDDEN * 2;
    ushort_t* h1b  = (ushort_t*)base; base += (size_t)N_NODES * HIDDEN * 2;
    float*    h2   = (float*)base;    base += (size_t)N_NODES * HIDDEN * 4;
    ushort_t* Wt1  = (ushort_t*)base; base += (size_t)IN_CH * QKV_COLS * 2;
    ushort_t* Wt2  = (ushort_t*)base; base += (size_t)HIDDEN * QKV_COLS * 2;
    float*    bcat1 = (float*)base;   base += QKV_COLS * 4;
    float*    bcat2 = (float*)base;   base += QKV_COLS * 4;
    float*    part = (float*)base;    base += (size_t)N_GRAPHS * 8 * 64 * 4;
    int*      deg  = (int*)base;      base += (size_t)N_NODES * 4;
    ushort_t* colb = (ushort_t*)base; base += ((size_t)N_NODES * MAXDEG + 64) * 2;
    ushort_t* xb   = (ushort_t*)base; base += (size_t)N_NODES * IN_CH * 2;  // bf16 x

    // slab (9.63MB) + cntm (0.2MB) alias h2 (12.8MB): dead before attn2
    // writes h2 (stream-ordered).
    uint_t* slab = (uint_t*)h2;
    int*    cntm = (int*)((char*)h2 + (size_t)NBUCK * P1B * SLABP * 4);

    const int RB = (N_NODES + 63) / 64;        // 782
    const int GG = 8 * 7 * ((RB + 7) / 8);     // 5488
    dim3 attn_block(64, 4);
    int attn_grid = (N_NODES + 3) / 4;         // 12500

    // ---- prep: weight concat || pass-1 bucket scatter || x->bf16 ----
    prep_p1<<<PREP_CONC_B + P1B + XCB, 256, 0, stream>>>(
        c1_Wq, c1_Wk, c1_Wv, c1_Ws, c1_bq, c1_bk, c1_bv, c1_bs,
        c2_Wq, c2_Wk, c2_Wv, c2_Ws, c2_bq, c2_bk, c2_bv, c2_bs,
        Wt1, Wt2, bcat1, bcat2, srcp, dstp, slab, cntm, x, xb);

    // ---- conv1 GEMM || pass-2 fine scatter (pass-2 blocks FIRST) ----
    gemm_fill12<IN_CH><<<NBUCK + GG, 256, 0, stream>>>(
        xb, Wt1, bcat1, qb8, kvb, skipb, N_NODES, RB, cntm, slab, deg, colb);
    attn_agg7<true><<<attn_grid, attn_block, 0, stream>>>(qb8, kvb, skipb, deg, colb, h1b);

    // ---- conv2 (A = h1b bf16) ----
    gemm_v12<HIDDEN><<<GG, 256, 0, stream>>>(h1b, Wt2, bcat2, qb8, kvb, skipb, N_NODES, RB);
    attn_agg7<false><<<attn_grid, attn_block, 0, stream>>>(qb8, kvb, skipb, deg, colb, h2);

    // ---- pool (parallel partial) + head ----
    pool_partial<<<N_GRAPHS * 8, 256, 0, stream>>>(h2, batch, part);
    head_mlp<<<N_GRAPHS, 256, 0, stream>>>(part, batch, gfeats,
                                           g_W1, g_b1, g_W2, g_b2,
                                           h_W1, h_b1, h_W2, h_b2, out);
}